// Round 4
// baseline (357.463 us; speedup 1.0000x reference)
//
#include <hip/hip_runtime.h>

typedef __attribute__((ext_vector_type(8))) short bf16x8;
typedef __attribute__((ext_vector_type(4))) float f32x4;

#define B_N 8192
#define D_N 256
#define K_N 64

__device__ __forceinline__ unsigned short bf16_rne(float f) {
  unsigned u = __builtin_bit_cast(unsigned, f);
  u += 0x7fffu + ((u >> 16) & 1u);
  return (unsigned short)(u >> 16);
}
__device__ __forceinline__ float bf16_f32(unsigned short h) {
  return __builtin_bit_cast(float, (unsigned)h << 16);
}

// DMA 16B/lane global->LDS. LDS dest: wave-uniform base + lane*16 (linear).
__device__ __forceinline__ void gload_lds16(const void* g, void* l) {
  __builtin_amdgcn_global_load_lds(
      (const __attribute__((address_space(1))) unsigned int*)g,
      (__attribute__((address_space(3))) unsigned int*)l, 16, 0, 0);
}

// One-time f32 -> bf16 (hi) + bf16 (residual lo) split.
__global__ void convert_kernel(const float* __restrict__ src,
                               ushort* __restrict__ hi, ushort* __restrict__ lo,
                               int n4) {
  int idx = blockIdx.x * blockDim.x + threadIdx.x;
  int stride = gridDim.x * blockDim.x;
  for (int i = idx; i < n4; i += stride) {
    float4 v = ((const float4*)src)[i];
    ushort4 h, l;
    h.x = bf16_rne(v.x); l.x = bf16_rne(v.x - bf16_f32(h.x));
    h.y = bf16_rne(v.y); l.y = bf16_rne(v.y - bf16_f32(h.y));
    h.z = bf16_rne(v.z); l.z = bf16_rne(v.z - bf16_f32(h.z));
    h.w = bf16_rne(v.w); l.w = bf16_rne(v.w - bf16_f32(h.w));
    ((ushort4*)hi)[i] = h;
    ((ushort4*)lo)[i] = l;
  }
}

// xsx[b][k] = x_b^T Sigma_k x_b.
// 256x256 tile, BK=64, 8 waves (2Mx4N), K' = 768 = 3 segments
// [Xh*Sh | Xl*Sh | Xh*Sl] (bf16-split, f32 accum).
// 4-phase-per-K-tile schedule with RAW s_barrier + COUNTED vmcnt (T3+T4):
//   tile head: issue 8 gload_lds for t+1 into buf^1, s_waitcnt vmcnt(8)
//   (tile t landed, t+1 in flight), barrier. Never vmcnt(0) except last tile.
//   phase: ds_read quadrant frags -> barrier -> setprio+16 MFMA -> barrier.
// Chunk-XOR swizzle p = c ^ (row&7) on global SOURCE (gload_lds writes
// linearly) and on the ds_read side -> 0 bank conflicts (round-3 verified).
// Fused epilogue: xsx[b] = sum_d Yp[b][d] * X[b][d] with exact f32 X.
__global__ __launch_bounds__(512, 2) void xsx256_kernel(
    const float* __restrict__ X,
    const ushort* __restrict__ Xh, const ushort* __restrict__ Xl,
    const ushort* __restrict__ Sh, const ushort* __restrict__ Sl,
    float* __restrict__ xsx) {
  constexpr int BM = 256, BK = 64;
  __shared__ __align__(16) ushort AB[2][2][BM * BK];  // 128 KB  [buf][A/B]
  __shared__ float red[4][BM];                        //   4 KB

  const int tid = threadIdx.x;
  const int lane = tid & 63;
  const int wid = tid >> 6;  // 0..7
  const int wm = wid >> 2;   // 0..1 : M half (128 rows)
  const int wn = wid & 3;    // 0..3 : N quarter (64 cols)
  const int lr = lane & 15;
  const int lk = lane >> 4;

  // XCD-aware mapping: each XCD owns 8 k values (Sigma set = 2 MB, L2-fits);
  // within an XCD, k varies fastest so co-resident blocks share the X tile.
  const int bid = blockIdx.x;
  const int xcd = bid & 7;
  const int j = bid >> 3;          // 0..255
  const int kk = xcd * 8 + (j & 7);
  const int bx = j >> 3;           // 0..31
  const int b0 = bx * BM;
  const size_t soff = (size_t)kk * D_N * D_N;

  // Staging swizzle: lane l covers LDS [row8 = l>>3][physical chunk = l&7];
  // it must READ global logical chunk (l&7) ^ (l>>3).
  const int sw_row = lane >> 3;
  const int sw_cs = (lane & 7) ^ sw_row;
  const size_t aoff = (size_t)(b0 + wid * 32 + sw_row) * D_N + sw_cs * 8;
  const size_t boff = soff + (size_t)(wid * 32 + sw_row) * D_N + sw_cs * 8;

  f32x4 acc[8][4];
#pragma unroll
  for (int mi = 0; mi < 8; ++mi)
#pragma unroll
    for (int ni = 0; ni < 4; ++ni) acc[mi][ni] = (f32x4){0.f, 0.f, 0.f, 0.f};

  auto stage = [&](int buf, int t) {
    const int seg = t >> 2;
    const int e0 = (t & 3) * 64;
    const ushort* pa = (seg == 1) ? Xl : Xh;
    const ushort* pb = (seg == 2) ? Sl : Sh;
#pragma unroll
    for (int i = 0; i < 4; ++i) {
      gload_lds16(pa + aoff + e0 + i * 8 * D_N,
                  &AB[buf][0][(wid * 32 + i * 8) * BK]);
      gload_lds16(pb + boff + e0 + i * 8 * D_N,
                  &AB[buf][1][(wid * 32 + i * 8) * BK]);
    }
  };

  stage(0, 0);  // 8 loads in flight; waited by t=0 head vmcnt

  for (int t = 0; t < 12; ++t) {
    const int cur = t & 1;
    const ushort* Ab = &AB[cur][0][0];
    const ushort* Bb = &AB[cur][1][0];
    // ---- tile head: prefetch t+1 into buf^1 (free: its tile-(t-1) reads
    // completed before the previous tile's final barrier), counted wait ----
    if (t < 11) {
      stage(cur ^ 1, t + 1);
      asm volatile("s_waitcnt vmcnt(8)" ::: "memory");  // tile t landed
    } else {
      asm volatile("s_waitcnt vmcnt(0)" ::: "memory");  // last tile: drain
    }
    __builtin_amdgcn_s_barrier();       // all waves see tile t in LDS
    __builtin_amdgcn_sched_barrier(0);  // pin ds_reads below the wait

    // ---- 4 phases: quadrants (mh2 x nh2), A-frags reused across nh2 ----
#pragma unroll
    for (int mh2 = 0; mh2 < 2; ++mh2) {
      bf16x8 a[4][2];
#pragma unroll
      for (int kh = 0; kh < 2; ++kh) {
        const int ksw = (((kh << 2) | lk) ^ (lr & 7)) * 8;
#pragma unroll
        for (int mi = 0; mi < 4; ++mi)
          a[mi][kh] = *(const bf16x8*)
              &Ab[(wm * 128 + (mh2 * 4 + mi) * 16 + lr) * BK + ksw];
      }
#pragma unroll
      for (int nh2 = 0; nh2 < 2; ++nh2) {
        bf16x8 bb[2][2];
#pragma unroll
        for (int kh = 0; kh < 2; ++kh) {
          const int ksw = (((kh << 2) | lk) ^ (lr & 7)) * 8;
#pragma unroll
          for (int ni = 0; ni < 2; ++ni)
            bb[ni][kh] = *(const bf16x8*)
                &Bb[(wn * 64 + (nh2 * 2 + ni) * 16 + lr) * BK + ksw];
        }
        __builtin_amdgcn_s_barrier();  // lockstep: ds_read -> MFMA together
        __builtin_amdgcn_s_setprio(1);
#pragma unroll
        for (int kh = 0; kh < 2; ++kh)
#pragma unroll
          for (int ni = 0; ni < 2; ++ni)
#pragma unroll
            for (int mi = 0; mi < 4; ++mi)
              acc[mh2 * 4 + mi][nh2 * 2 + ni] =
                  __builtin_amdgcn_mfma_f32_16x16x32_bf16(
                      a[mi][kh], bb[ni][kh], acc[mh2 * 4 + mi][nh2 * 2 + ni],
                      0, 0, 0);
        __builtin_amdgcn_s_setprio(0);
        __builtin_amdgcn_sched_barrier(0);
        __builtin_amdgcn_s_barrier();  // phase end
      }
    }
  }

  // Epilogue: dot with exact f32 X. C/D layout: col=lane&15, row=(lane>>4)*4+j.
#pragma unroll
  for (int mi = 0; mi < 8; ++mi) {
#pragma unroll
    for (int jj = 0; jj < 4; ++jj) {
      const int rloc = wm * 128 + mi * 16 + lk * 4 + jj;
      const float* xr = X + (size_t)(b0 + rloc) * D_N + wn * 64 + lr;
      float p = 0.f;
#pragma unroll
      for (int ni = 0; ni < 4; ++ni) p = fmaf(acc[mi][ni][jj], xr[ni * 16], p);
      p += __shfl_xor(p, 1);
      p += __shfl_xor(p, 2);
      p += __shfl_xor(p, 4);
      p += __shfl_xor(p, 8);
      if (lr == 0) red[wn][rloc] = p;
    }
  }
  __syncthreads();
  if (tid < BM) {
    const float s = red[0][tid] + red[1][tid] + red[2][tid] + red[3][tid];
    xsx[(size_t)(b0 + tid) * K_N + kk] = s;
  }
}

// Fallback (small ws): in-block convert, 128-tile (round-1 verified path).
__global__ __launch_bounds__(512, 2) void xsx_fallback(
    const float* __restrict__ X, const float* __restrict__ Sigma,
    float* __restrict__ xsx) {
  constexpr int BM = 128, KT = 32;
  __shared__ __align__(16) ushort Ah[BM][KT];
  __shared__ __align__(16) ushort Al[BM][KT];
  __shared__ __align__(16) ushort Bh[D_N][KT];
  __shared__ __align__(16) ushort Bl[D_N][KT];
  __shared__ float red[4][BM];

  const int tid = threadIdx.x;
  const int lane = tid & 63;
  const int wid = tid >> 6;
  const int wm = wid >> 2;
  const int wn = wid & 3;
  const int lr = lane & 15;
  const int lk = lane >> 4;

  const int b0 = blockIdx.x * BM;
  const int kk = blockIdx.y;
  const size_t soff = (size_t)kk * D_N * D_N;

  f32x4 acc[4][4];
#pragma unroll
  for (int mi = 0; mi < 4; ++mi)
#pragma unroll
    for (int ni = 0; ni < 4; ++ni) acc[mi][ni] = (f32x4){0.f, 0.f, 0.f, 0.f};

  for (int ec = 0; ec < D_N / KT; ++ec) {
    const int e0 = ec * KT;
    __syncthreads();
#pragma unroll
    for (int r = 0; r < 2; ++r) {
      const int i = tid + 512 * r;
      const int row = i >> 3, c4 = (i & 7) * 4;
      const float4 v = *(const float4*)(X + (size_t)(b0 + row) * D_N + e0 + c4);
      ushort4 h, l;
      h.x = bf16_rne(v.x); l.x = bf16_rne(v.x - bf16_f32(h.x));
      h.y = bf16_rne(v.y); l.y = bf16_rne(v.y - bf16_f32(h.y));
      h.z = bf16_rne(v.z); l.z = bf16_rne(v.z - bf16_f32(h.z));
      h.w = bf16_rne(v.w); l.w = bf16_rne(v.w - bf16_f32(h.w));
      *(ushort4*)&Ah[row][c4] = h;
      *(ushort4*)&Al[row][c4] = l;
    }
#pragma unroll
    for (int r = 0; r < 4; ++r) {
      const int i = tid + 512 * r;
      const int d = i >> 3, c4 = (i & 7) * 4;
      const float4 v = *(const float4*)(Sigma + soff + (size_t)d * D_N + e0 + c4);
      ushort4 h, l;
      h.x = bf16_rne(v.x); l.x = bf16_rne(v.x - bf16_f32(h.x));
      h.y = bf16_rne(v.y); l.y = bf16_rne(v.y - bf16_f32(h.y));
      h.z = bf16_rne(v.z); l.z = bf16_rne(v.z - bf16_f32(h.z));
      h.w = bf16_rne(v.w); l.w = bf16_rne(v.w - bf16_f32(h.w));
      *(ushort4*)&Bh[d][c4] = h;
      *(ushort4*)&Bl[d][c4] = l;
    }
    __syncthreads();

    bf16x8 ah[4], al[4];
#pragma unroll
    for (int mi = 0; mi < 4; ++mi) {
      ah[mi] = *(const bf16x8*)&Ah[wm * 64 + mi * 16 + lr][lk * 8];
      al[mi] = *(const bf16x8*)&Al[wm * 64 + mi * 16 + lr][lk * 8];
    }
#pragma unroll
    for (int ni = 0; ni < 4; ++ni) {
      const bf16x8 bh = *(const bf16x8*)&Bh[wn * 64 + ni * 16 + lr][lk * 8];
      const bf16x8 bl = *(const bf16x8*)&Bl[wn * 64 + ni * 16 + lr][lk * 8];
#pragma unroll
      for (int mi = 0; mi < 4; ++mi) {
        acc[mi][ni] = __builtin_amdgcn_mfma_f32_16x16x32_bf16(ah[mi], bh, acc[mi][ni], 0, 0, 0);
        acc[mi][ni] = __builtin_amdgcn_mfma_f32_16x16x32_bf16(al[mi], bh, acc[mi][ni], 0, 0, 0);
        acc[mi][ni] = __builtin_amdgcn_mfma_f32_16x16x32_bf16(ah[mi], bl, acc[mi][ni], 0, 0, 0);
      }
    }
  }

  float p[4][4];
#pragma unroll
  for (int mi = 0; mi < 4; ++mi)
#pragma unroll
    for (int j = 0; j < 4; ++j) p[mi][j] = 0.f;
#pragma unroll
  for (int mi = 0; mi < 4; ++mi) {
#pragma unroll
    for (int j = 0; j < 4; ++j) {
      const int brow = b0 + wm * 64 + mi * 16 + lk * 4 + j;
      const float* xr = X + (size_t)brow * D_N + wn * 64 + lr;
#pragma unroll
      for (int ni = 0; ni < 4; ++ni)
        p[mi][j] = fmaf(acc[mi][ni][j], xr[ni * 16], p[mi][j]);
    }
  }
#pragma unroll
  for (int mi = 0; mi < 4; ++mi)
#pragma unroll
    for (int j = 0; j < 4; ++j) {
      float v = p[mi][j];
      v += __shfl_xor(v, 1);
      v += __shfl_xor(v, 2);
      v += __shfl_xor(v, 4);
      v += __shfl_xor(v, 8);
      p[mi][j] = v;
    }
  if (lr == 0) {
#pragma unroll
    for (int mi = 0; mi < 4; ++mi)
#pragma unroll
      for (int j = 0; j < 4; ++j)
        red[wn][wm * 64 + mi * 16 + lk * 4 + j] = p[mi][j];
  }
  __syncthreads();
  if (tid < BM) {
    const float s = red[0][tid] + red[1][tid] + red[2][tid] + red[3][tid];
    xsx[(size_t)(b0 + tid) * K_N + kk] = s;
  }
}

// One wave per batch row b; lane k owns class k in [0,64).
__global__ __launch_bounds__(256) void loss_kernel(
    const float* __restrict__ X, const int* __restrict__ y,
    const float* __restrict__ mu, const int* __restrict__ loss_type,
    const float* __restrict__ xsx, float* __restrict__ out) {
  __shared__ float mu_s[D_N * K_N];  // 64 KB
  __shared__ float x_s[4][D_N];      //  4 KB
  const int tid = threadIdx.x;
  const int wid = tid >> 6;
  const int lane = tid & 63;
  const int b = blockIdx.x * 4 + wid;

  for (int i = tid; i < D_N * K_N / 4; i += 256)
    ((float4*)mu_s)[i] = ((const float4*)mu)[i];
  ((float4*)&x_s[wid][0])[lane] = ((const float4*)(X + (size_t)b * D_N))[lane];
  __syncthreads();

  const int yb = y[b];
  const int lt = loss_type[0];

  float logit = 0.f;
#pragma unroll 8
  for (int d = 0; d < D_N; ++d)
    logit = fmaf(x_s[wid][d], mu_s[d * K_N + lane], logit);

  float term;
  if (lt == 1) {
    const float xv = xsx[(size_t)b * K_N + lane];
    const float psi = sqrtf(fmaxf(xv + logit * logit, 0.f));
    const float bk = (lane <= yb) ? 1.f : 0.f;
    const float kap = ((lane == yb) ? 1.f : 0.f) - 0.5f * bk;
    // psi/2 - softplus(psi) = -psi/2 - log1p(exp(-psi)) for psi >= 0
    term = logit * kap + bk * (-0.5f * psi - log1pf(expf(-psi)));
  } else {
    const float sp = (logit > 0.f) ? (logit + log1pf(expf(-logit)))
                                   : log1pf(expf(logit));
    term = ((lane == yb) ? logit : 0.f) - ((lane <= yb) ? sp : 0.f);
  }
#pragma unroll
  for (int s = 1; s < 64; s <<= 1) term += __shfl_xor(term, s);
  if (lane == 0) out[b] = -term;
}

extern "C" void kernel_launch(void* const* d_in, const int* in_sizes, int n_in,
                              void* d_out, int out_size, void* d_ws, size_t ws_size,
                              hipStream_t stream) {
  const float* X = (const float*)d_in[0];
  const int* y = (const int*)d_in[1];
  const float* mu = (const float*)d_in[2];
  const float* Sigma = (const float*)d_in[3];
  const int* lt = (const int*)d_in[4];
  float* out = (float*)d_out;

  const size_t XN = (size_t)B_N * D_N;        // 2,097,152 elems
  const size_t SN = (size_t)K_N * D_N * D_N;  // 4,194,304 elems
  const size_t xh_off = 0;
  const size_t xl_off = xh_off + XN * 2;
  const size_t sh_off = xl_off + XN * 2;
  const size_t sl_off = sh_off + SN * 2;
  const size_t xsx_off = sl_off + SN * 2;
  const size_t need = xsx_off + (size_t)B_N * K_N * 4;  // ~27.3 MB

  char* w = (char*)d_ws;
  if (ws_size >= need) {
    ushort* Xh = (ushort*)(w + xh_off);
    ushort* Xl = (ushort*)(w + xl_off);
    ushort* Sh = (ushort*)(w + sh_off);
    ushort* Sl = (ushort*)(w + sl_off);
    float* xsx = (float*)(w + xsx_off);
    hipLaunchKernelGGL(convert_kernel, dim3(1024), dim3(256), 0, stream,
                       X, Xh, Xl, (int)(XN / 4));
    hipLaunchKernelGGL(convert_kernel, dim3(2048), dim3(256), 0, stream,
                       Sigma, Sh, Sl, (int)(SN / 4));
    hipLaunchKernelGGL(xsx256_kernel, dim3(2048), dim3(512), 0, stream,
                       X, Xh, Xl, Sh, Sl, xsx);
    hipLaunchKernelGGL(loss_kernel, dim3(B_N / 4), dim3(256), 0, stream,
                       X, y, mu, lt, xsx, out);
  } else {
    float* xsx = (float*)w;  // needs 2 MB
    hipLaunchKernelGGL(xsx_fallback, dim3(B_N / 128, K_N), dim3(512), 0, stream,
                       X, Sigma, xsx);
    hipLaunchKernelGGL(loss_kernel, dim3(B_N / 4), dim3(256), 0, stream,
                       X, y, mu, lt, xsx, out);
  }
}

// Round 5
// 345.375 us; speedup vs baseline: 1.0350x; 1.0350x over previous
//
#include <hip/hip_runtime.h>

typedef __attribute__((ext_vector_type(8))) short bf16x8;
typedef __attribute__((ext_vector_type(4))) float f32x4;

#define B_N 8192
#define D_N 256
#define K_N 64

__device__ __forceinline__ unsigned short bf16_rne(float f) {
  unsigned u = __builtin_bit_cast(unsigned, f);
  u += 0x7fffu + ((u >> 16) & 1u);
  return (unsigned short)(u >> 16);
}
__device__ __forceinline__ float bf16_f32(unsigned short h) {
  return __builtin_bit_cast(float, (unsigned)h << 16);
}

// DMA 16B/lane global->LDS. LDS dest: wave-uniform base + lane*16 (linear).
__device__ __forceinline__ void gload_lds16(const void* g, void* l) {
  __builtin_amdgcn_global_load_lds(
      (const __attribute__((address_space(1))) unsigned int*)g,
      (__attribute__((address_space(3))) unsigned int*)l, 16, 0, 0);
}

// One-time f32 -> bf16 (hi) + bf16 (residual lo) split.
__global__ void convert_kernel(const float* __restrict__ src,
                               ushort* __restrict__ hi, ushort* __restrict__ lo,
                               int n4) {
  int idx = blockIdx.x * blockDim.x + threadIdx.x;
  int stride = gridDim.x * blockDim.x;
  for (int i = idx; i < n4; i += stride) {
    float4 v = ((const float4*)src)[i];
    ushort4 h, l;
    h.x = bf16_rne(v.x); l.x = bf16_rne(v.x - bf16_f32(h.x));
    h.y = bf16_rne(v.y); l.y = bf16_rne(v.y - bf16_f32(h.y));
    h.z = bf16_rne(v.z); l.z = bf16_rne(v.z - bf16_f32(h.z));
    h.w = bf16_rne(v.w); l.w = bf16_rne(v.w - bf16_f32(h.w));
    ((ushort4*)hi)[i] = h;
    ((ushort4*)lo)[i] = l;
  }
}

// xsx[b][k] = x_b^T Sigma_k x_b.  128x256 tile (BM=128 b-rows, full d), 8
// waves (2Mx4N, 64x64 wave tiles), KT=32 e-chunks, 3-term bf16 split
// [Xh*Sh | Xh*Sl | Xl*Sh] accumulated in f32.
// KEY CHANGE vs prior rounds: A (X) fragments load DIRECTLY global->VGPR
// (16 rows x 64B lines; X is L2-hot, re-read by all 64 k-blocks) -- no LDS,
// no barrier dependency, VMEM pipe instead of the contended LDS pipe.
// LDS holds ONLY Sigma (Bh/Bl, 32 KB single-buffered via gload_lds) with a
// 4-chunk XOR swizzle (phys_chunk = c ^ ((row>>1)&3), both-sides) -> 2-way
// max bank aliasing (free). XCD-bijective k-major block mapping keeps each
// XCD's 8 Sigma_k set (2 MB) L2-resident. setprio(1) around MFMA clusters.
// Fused epilogue: xsx[b] = sum_d Yp[b][d] * X[b][d] with exact f32 X.
__global__ __launch_bounds__(512, 4) void xsx_kernel2(
    const float* __restrict__ X,
    const ushort* __restrict__ Xh, const ushort* __restrict__ Xl,
    const ushort* __restrict__ Sh, const ushort* __restrict__ Sl,
    float* __restrict__ xsx) {
  constexpr int BM = 128, KT = 32;
  __shared__ __align__(16) ushort Bh[D_N][KT];  // 16 KB  Sigma hi [d][e-sw]
  __shared__ __align__(16) ushort Bl[D_N][KT];  // 16 KB  Sigma lo
  __shared__ float red[4][BM];                  //  2 KB

  const int tid = threadIdx.x;
  const int lane = tid & 63;
  const int wid = tid >> 6;  // 0..7
  const int wm = wid >> 2;   // 0..1 : M half (64 rows)
  const int wn = wid & 3;    // 0..3 : N quarter (64 d-cols)
  const int lr = lane & 15;
  const int lk = lane >> 4;

  // XCD-bijective mapping: xcd owns k in [xcd*8, xcd*8+8); k varies fastest
  // so co-resident blocks on one XCD share the X panel and Sigma stays hot.
  const int bid = blockIdx.x;  // 4096 = 8 * 512
  const int xcd = bid & 7;
  const int j = bid >> 3;          // 0..511
  const int kk = xcd * 8 + (j & 7);
  const int b0 = (j >> 3) * BM;    // 0..63 -> row block
  const size_t soff = (size_t)kk * D_N * D_N;

  // Sigma staging: lane l covers LDS [row16 = l>>2][phys chunk = l&3]; it
  // reads global logical chunk (l&3) ^ ((l>>3)&3)  ( == (row>>1)&3 ).
  const int srow = lane >> 2;                          // 0..15
  const int sc = ((lane & 3) ^ ((lane >> 3) & 3)) * 8; // swizzled ushort col
  const size_t g0 = soff + (size_t)(wid * 16 + srow) * D_N + sc;

  // ds_read side of the swizzle: phys chunk = lk ^ ((lr>>1)&3).
  const int rdc = (lk ^ ((lr >> 1) & 3)) * 8;

  f32x4 acc[4][4];
#pragma unroll
  for (int mi = 0; mi < 4; ++mi)
#pragma unroll
    for (int ni = 0; ni < 4; ++ni) acc[mi][ni] = (f32x4){0.f, 0.f, 0.f, 0.f};

  const size_t arow = (size_t)(b0 + wm * 64 + lr) * D_N + lk * 8;

  for (int ec = 0; ec < D_N / KT; ++ec) {
    const int e0 = ec * KT;
    __syncthreads();  // all reads of previous Sigma chunk done
    gload_lds16(Sh + g0 + e0, &Bh[wid * 16][0]);
    gload_lds16(Sh + g0 + e0 + (size_t)128 * D_N, &Bh[128 + wid * 16][0]);
    gload_lds16(Sl + g0 + e0, &Bl[wid * 16][0]);
    gload_lds16(Sl + g0 + e0 + (size_t)128 * D_N, &Bl[128 + wid * 16][0]);
    // A-frags (X hi) direct from global: used by segments 0 and 1.
    bf16x8 ah[4];
#pragma unroll
    for (int mi = 0; mi < 4; ++mi)
      ah[mi] = *(const bf16x8*)(Xh + arow + mi * 16 * D_N + e0);
    __syncthreads();  // compiler drains vmcnt(0): Sigma in LDS, ah in regs

    // seg 0: Xh * Sh
#pragma unroll
    for (int ni = 0; ni < 4; ++ni) {
      const bf16x8 b = *(const bf16x8*)&Bh[wn * 64 + ni * 16 + lr][rdc];
      __builtin_amdgcn_s_setprio(1);
#pragma unroll
      for (int mi = 0; mi < 4; ++mi)
        acc[mi][ni] = __builtin_amdgcn_mfma_f32_16x16x32_bf16(
            ah[mi], b, acc[mi][ni], 0, 0, 0);
      __builtin_amdgcn_s_setprio(0);
    }
    // seg 1: Xh * Sl
#pragma unroll
    for (int ni = 0; ni < 4; ++ni) {
      const bf16x8 b = *(const bf16x8*)&Bl[wn * 64 + ni * 16 + lr][rdc];
      __builtin_amdgcn_s_setprio(1);
#pragma unroll
      for (int mi = 0; mi < 4; ++mi)
        acc[mi][ni] = __builtin_amdgcn_mfma_f32_16x16x32_bf16(
            ah[mi], b, acc[mi][ni], 0, 0, 0);
      __builtin_amdgcn_s_setprio(0);
    }
    // seg 2: Xl * Sh  (al loads issue here; latency hides under seg0/seg1)
    bf16x8 al[4];
#pragma unroll
    for (int mi = 0; mi < 4; ++mi)
      al[mi] = *(const bf16x8*)(Xl + arow + mi * 16 * D_N + e0);
#pragma unroll
    for (int ni = 0; ni < 4; ++ni) {
      const bf16x8 b = *(const bf16x8*)&Bh[wn * 64 + ni * 16 + lr][rdc];
      __builtin_amdgcn_s_setprio(1);
#pragma unroll
      for (int mi = 0; mi < 4; ++mi)
        acc[mi][ni] = __builtin_amdgcn_mfma_f32_16x16x32_bf16(
            al[mi], b, acc[mi][ni], 0, 0, 0);
      __builtin_amdgcn_s_setprio(0);
    }
  }

  // Epilogue: dot with exact f32 X. C/D layout: col=lane&15, row=(lane>>4)*4+j.
  float p[4][4];
#pragma unroll
  for (int mi = 0; mi < 4; ++mi)
#pragma unroll
    for (int jj = 0; jj < 4; ++jj) p[mi][jj] = 0.f;

#pragma unroll
  for (int mi = 0; mi < 4; ++mi) {
#pragma unroll
    for (int jj = 0; jj < 4; ++jj) {
      const int brow = b0 + wm * 64 + mi * 16 + lk * 4 + jj;
      const float* xr = X + (size_t)brow * D_N + wn * 64 + lr;
#pragma unroll
      for (int ni = 0; ni < 4; ++ni)
        p[mi][jj] = fmaf(acc[mi][ni][jj], xr[ni * 16], p[mi][jj]);
    }
  }
#pragma unroll
  for (int mi = 0; mi < 4; ++mi)
#pragma unroll
    for (int jj = 0; jj < 4; ++jj) {
      float v = p[mi][jj];
      v += __shfl_xor(v, 1);
      v += __shfl_xor(v, 2);
      v += __shfl_xor(v, 4);
      v += __shfl_xor(v, 8);
      p[mi][jj] = v;
    }
  if (lr == 0) {
#pragma unroll
    for (int mi = 0; mi < 4; ++mi)
#pragma unroll
      for (int jj = 0; jj < 4; ++jj)
        red[wn][wm * 64 + mi * 16 + lk * 4 + jj] = p[mi][jj];
  }
  __syncthreads();
  if (tid < BM) {
    const float s = red[0][tid] + red[1][tid] + red[2][tid] + red[3][tid];
    xsx[(size_t)(b0 + tid) * K_N + kk] = s;
  }
}

// Fallback (small ws): in-block convert, 128-tile (round-1 verified path).
__global__ __launch_bounds__(512, 2) void xsx_fallback(
    const float* __restrict__ X, const float* __restrict__ Sigma,
    float* __restrict__ xsx) {
  constexpr int BM = 128, KT = 32;
  __shared__ __align__(16) ushort Ah[BM][KT];
  __shared__ __align__(16) ushort Al[BM][KT];
  __shared__ __align__(16) ushort Bh[D_N][KT];
  __shared__ __align__(16) ushort Bl[D_N][KT];
  __shared__ float red[4][BM];

  const int tid = threadIdx.x;
  const int lane = tid & 63;
  const int wid = tid >> 6;
  const int wm = wid >> 2;
  const int wn = wid & 3;
  const int lr = lane & 15;
  const int lk = lane >> 4;

  const int b0 = blockIdx.x * BM;
  const int kk = blockIdx.y;
  const size_t soff = (size_t)kk * D_N * D_N;

  f32x4 acc[4][4];
#pragma unroll
  for (int mi = 0; mi < 4; ++mi)
#pragma unroll
    for (int ni = 0; ni < 4; ++ni) acc[mi][ni] = (f32x4){0.f, 0.f, 0.f, 0.f};

  for (int ec = 0; ec < D_N / KT; ++ec) {
    const int e0 = ec * KT;
    __syncthreads();
#pragma unroll
    for (int r = 0; r < 2; ++r) {
      const int i = tid + 512 * r;
      const int row = i >> 3, c4 = (i & 7) * 4;
      const float4 v = *(const float4*)(X + (size_t)(b0 + row) * D_N + e0 + c4);
      ushort4 h, l;
      h.x = bf16_rne(v.x); l.x = bf16_rne(v.x - bf16_f32(h.x));
      h.y = bf16_rne(v.y); l.y = bf16_rne(v.y - bf16_f32(h.y));
      h.z = bf16_rne(v.z); l.z = bf16_rne(v.z - bf16_f32(h.z));
      h.w = bf16_rne(v.w); l.w = bf16_rne(v.w - bf16_f32(h.w));
      *(ushort4*)&Ah[row][c4] = h;
      *(ushort4*)&Al[row][c4] = l;
    }
#pragma unroll
    for (int r = 0; r < 4; ++r) {
      const int i = tid + 512 * r;
      const int d = i >> 3, c4 = (i & 7) * 4;
      const float4 v = *(const float4*)(Sigma + soff + (size_t)d * D_N + e0 + c4);
      ushort4 h, l;
      h.x = bf16_rne(v.x); l.x = bf16_rne(v.x - bf16_f32(h.x));
      h.y = bf16_rne(v.y); l.y = bf16_rne(v.y - bf16_f32(h.y));
      h.z = bf16_rne(v.z); l.z = bf16_rne(v.z - bf16_f32(h.z));
      h.w = bf16_rne(v.w); l.w = bf16_rne(v.w - bf16_f32(h.w));
      *(ushort4*)&Bh[d][c4] = h;
      *(ushort4*)&Bl[d][c4] = l;
    }
    __syncthreads();

    bf16x8 ah[4], al[4];
#pragma unroll
    for (int mi = 0; mi < 4; ++mi) {
      ah[mi] = *(const bf16x8*)&Ah[wm * 64 + mi * 16 + lr][lk * 8];
      al[mi] = *(const bf16x8*)&Al[wm * 64 + mi * 16 + lr][lk * 8];
    }
#pragma unroll
    for (int ni = 0; ni < 4; ++ni) {
      const bf16x8 bh = *(const bf16x8*)&Bh[wn * 64 + ni * 16 + lr][lk * 8];
      const bf16x8 bl = *(const bf16x8*)&Bl[wn * 64 + ni * 16 + lr][lk * 8];
#pragma unroll
      for (int mi = 0; mi < 4; ++mi) {
        acc[mi][ni] = __builtin_amdgcn_mfma_f32_16x16x32_bf16(ah[mi], bh, acc[mi][ni], 0, 0, 0);
        acc[mi][ni] = __builtin_amdgcn_mfma_f32_16x16x32_bf16(al[mi], bh, acc[mi][ni], 0, 0, 0);
        acc[mi][ni] = __builtin_amdgcn_mfma_f32_16x16x32_bf16(ah[mi], bl, acc[mi][ni], 0, 0, 0);
      }
    }
  }

  float p[4][4];
#pragma unroll
  for (int mi = 0; mi < 4; ++mi)
#pragma unroll
    for (int jj = 0; jj < 4; ++jj) p[mi][jj] = 0.f;
#pragma unroll
  for (int mi = 0; mi < 4; ++mi) {
#pragma unroll
    for (int jj = 0; jj < 4; ++jj) {
      const int brow = b0 + wm * 64 + mi * 16 + lk * 4 + jj;
      const float* xr = X + (size_t)brow * D_N + wn * 64 + lr;
#pragma unroll
      for (int ni = 0; ni < 4; ++ni)
        p[mi][jj] = fmaf(acc[mi][ni][jj], xr[ni * 16], p[mi][jj]);
    }
  }
#pragma unroll
  for (int mi = 0; mi < 4; ++mi)
#pragma unroll
    for (int jj = 0; jj < 4; ++jj) {
      float v = p[mi][jj];
      v += __shfl_xor(v, 1);
      v += __shfl_xor(v, 2);
      v += __shfl_xor(v, 4);
      v += __shfl_xor(v, 8);
      p[mi][jj] = v;
    }
  if (lr == 0) {
#pragma unroll
    for (int mi = 0; mi < 4; ++mi)
#pragma unroll
      for (int jj = 0; jj < 4; ++jj)
        red[wn][wm * 64 + mi * 16 + lk * 4 + jj] = p[mi][jj];
  }
  __syncthreads();
  if (tid < BM) {
    const float s = red[0][tid] + red[1][tid] + red[2][tid] + red[3][tid];
    xsx[(size_t)(b0 + tid) * K_N + kk] = s;
  }
}

// One wave per batch row b; lane k owns class k in [0,64).
__global__ __launch_bounds__(256) void loss_kernel(
    const float* __restrict__ X, const int* __restrict__ y,
    const float* __restrict__ mu, const int* __restrict__ loss_type,
    const float* __restrict__ xsx, float* __restrict__ out) {
  __shared__ float mu_s[D_N * K_N];  // 64 KB
  __shared__ float x_s[4][D_N];      //  4 KB
  const int tid = threadIdx.x;
  const int wid = tid >> 6;
  const int lane = tid & 63;
  const int b = blockIdx.x * 4 + wid;

  for (int i = tid; i < D_N * K_N / 4; i += 256)
    ((float4*)mu_s)[i] = ((const float4*)mu)[i];
  ((float4*)&x_s[wid][0])[lane] = ((const float4*)(X + (size_t)b * D_N))[lane];
  __syncthreads();

  const int yb = y[b];
  const int lt = loss_type[0];

  float logit = 0.f;
#pragma unroll 8
  for (int d = 0; d < D_N; ++d)
    logit = fmaf(x_s[wid][d], mu_s[d * K_N + lane], logit);

  float term;
  if (lt == 1) {
    const float xv = xsx[(size_t)b * K_N + lane];
    const float psi = sqrtf(fmaxf(xv + logit * logit, 0.f));
    const float bk = (lane <= yb) ? 1.f : 0.f;
    const float kap = ((lane == yb) ? 1.f : 0.f) - 0.5f * bk;
    // psi/2 - softplus(psi) = -psi/2 - log1p(exp(-psi)) for psi >= 0
    term = logit * kap + bk * (-0.5f * psi - log1pf(expf(-psi)));
  } else {
    const float sp = (logit > 0.f) ? (logit + log1pf(expf(-logit)))
                                   : log1pf(expf(logit));
    term = ((lane == yb) ? logit : 0.f) - ((lane <= yb) ? sp : 0.f);
  }
#pragma unroll
  for (int s = 1; s < 64; s <<= 1) term += __shfl_xor(term, s);
  if (lane == 0) out[b] = -term;
}

extern "C" void kernel_launch(void* const* d_in, const int* in_sizes, int n_in,
                              void* d_out, int out_size, void* d_ws, size_t ws_size,
                              hipStream_t stream) {
  const float* X = (const float*)d_in[0];
  const int* y = (const int*)d_in[1];
  const float* mu = (const float*)d_in[2];
  const float* Sigma = (const float*)d_in[3];
  const int* lt = (const int*)d_in[4];
  float* out = (float*)d_out;

  const size_t XN = (size_t)B_N * D_N;        // 2,097,152 elems
  const size_t SN = (size_t)K_N * D_N * D_N;  // 4,194,304 elems
  const size_t xh_off = 0;
  const size_t xl_off = xh_off + XN * 2;
  const size_t sh_off = xl_off + XN * 2;
  const size_t sl_off = sh_off + SN * 2;
  const size_t xsx_off = sl_off + SN * 2;
  const size_t need = xsx_off + (size_t)B_N * K_N * 4;  // ~27.3 MB

  char* w = (char*)d_ws;
  if (ws_size >= need) {
    ushort* Xh = (ushort*)(w + xh_off);
    ushort* Xl = (ushort*)(w + xl_off);
    ushort* Sh = (ushort*)(w + sh_off);
    ushort* Sl = (ushort*)(w + sl_off);
    float* xsx = (float*)(w + xsx_off);
    hipLaunchKernelGGL(convert_kernel, dim3(1024), dim3(256), 0, stream,
                       X, Xh, Xl, (int)(XN / 4));
    hipLaunchKernelGGL(convert_kernel, dim3(2048), dim3(256), 0, stream,
                       Sigma, Sh, Sl, (int)(SN / 4));
    hipLaunchKernelGGL(xsx_kernel2, dim3(4096), dim3(512), 0, stream,
                       X, Xh, Xl, Sh, Sl, xsx);
    hipLaunchKernelGGL(loss_kernel, dim3(B_N / 4), dim3(256), 0, stream,
                       X, y, mu, lt, xsx, out);
  } else {
    float* xsx = (float*)w;  // needs 2 MB
    hipLaunchKernelGGL(xsx_fallback, dim3(B_N / 128, K_N), dim3(512), 0, stream,
                       X, Sigma, xsx);
    hipLaunchKernelGGL(loss_kernel, dim3(B_N / 4), dim3(256), 0, stream,
                       X, y, mu, lt, xsx, out);
  }
}